// Round 12
// baseline (531.799 us; speedup 1.0000x reference)
//
#include <hip/hip_runtime.h>

typedef unsigned short u16;
typedef u16 u16x8 __attribute__((ext_vector_type(8)));
typedef u16 u16x4 __attribute__((ext_vector_type(4)));
typedef __bf16 bf16x8 __attribute__((ext_vector_type(8)));
typedef float f32x4 __attribute__((ext_vector_type(4)));

#define Bn   4
#define Nn   3072
#define DIMn 768
#define Hn   3
#define HDn  256
#define BHn  12
#define Dn   262
#define EP   272      // e-rows padded to 17*16
#define MSn  8        // rc m-slices
#define FP   264      // fund e-pitch (262 padded to 4-float multiple)
#define KSn  4        // fund K-split: 300 -> 1200 blocks

__device__ __forceinline__ u16 f2bf(float f) {
    unsigned u = __builtin_bit_cast(unsigned, f);
    u += 0x7fffu + ((u >> 16) & 1u);
    return (u16)(u >> 16);
}
__device__ __forceinline__ float bf2f(u16 h) {
    unsigned u = ((unsigned)h) << 16;
    return __builtin_bit_cast(float, u);
}
__device__ __forceinline__ bf16x8 ld_frag16(const u16* p) {   // 16B-aligned read
    return *(const bf16x8*)p;
}
#define MFMA(a,b,c) __builtin_amdgcn_mfma_f32_16x16x32_bf16(a, b, c, 0, 0, 0)

// ---------------------------------------------------------------------------
// K0: fp32 -> bf16 elementwise (x and W pre-conversion)
// ---------------------------------------------------------------------------
__global__ void to_bf16(const float* __restrict__ in, u16* __restrict__ out, int n8) {
    int i = blockIdx.x * blockDim.x + threadIdx.x;
    if (i >= n8) return;
    float4 a = *(const float4*)(in + (size_t)i*8);
    float4 b = *(const float4*)(in + (size_t)i*8 + 4);
    u16x8 o;
    o[0]=f2bf(a.x); o[1]=f2bf(a.y); o[2]=f2bf(a.z); o[3]=f2bf(a.w);
    o[4]=f2bf(b.x); o[5]=f2bf(b.y); o[6]=f2bf(b.z); o[7]=f2bf(b.w);
    *(u16x8*)(out + (size_t)i*8) = o;
}

// ---------------------------------------------------------------------------
// K0b: WpfT[j][o] = Wpf[o][j]  (fp32, LDS-bounce transpose).
// ---------------------------------------------------------------------------
__global__ __launch_bounds__(256) void transpose_wpf(const float* __restrict__ Wpf,
                                                     float* __restrict__ WpfT) {
    __shared__ float tile[32][33];
    int jt = blockIdx.x * 32;   // 25 tiles over 786
    int ot = blockIdx.y * 32;   // 24 tiles over 768
    int tx = threadIdx.x & 31, ty = threadIdx.x >> 5;   // ty 0..7
    #pragma unroll
    for (int k = 0; k < 4; ++k) {
        int o = ot + ty + 8*k;
        int j = jt + tx;
        tile[ty + 8*k][tx] = (j < 786) ? Wpf[(size_t)o*786 + j] : 0.0f;
    }
    __syncthreads();
    #pragma unroll
    for (int k = 0; k < 4; ++k) {
        int j = jt + ty + 8*k;
        if (j < 786) WpfT[(size_t)j*768 + ot + tx] = tile[tx][ty + 8*k];
    }
}

// ---------------------------------------------------------------------------
// K1 (R21): qkv = x @ W_qkv^T, 128x128 tile, 4x4 acc/wave, reg-prefetch
// staging, XCD-chunked swizzle. Closed branch: gll/LDS-swizzle (R20) and
// fetch reduction (R21) both left dur at ~73.5us — structure is at its
// 2-barrier ceiling (~592 TF, above m97's shape curve at this size).
// ---------------------------------------------------------------------------
__global__ __launch_bounds__(256) void qkv_mfma(const u16* __restrict__ xb,
                                                const u16* __restrict__ Wb,
                                                u16* __restrict__ qh,
                                                u16* __restrict__ kh,
                                                u16* __restrict__ vT) {
    __shared__ u16 Pool[2*128*72];          // Xs | Ws; reused as C bounce
    u16* Xs = Pool;
    u16* Ws = Pool + 128*72;
    int tid = threadIdx.x;
    int w = tid >> 6, lane = tid & 63, quad = lane >> 4, l15 = lane & 15;
    // XCD-chunked remap: hw linear id -> contiguous work range per XCD
    int lid = blockIdx.x + 18*blockIdx.y;           // nwg = 1728
    int swz = (lid & 7)*216 + (lid >> 3);
    int cb = swz % 18, rb = swz / 18;
    int r0 = rb * 128;
    int b_ = rb / 24;
    int n0 = (rb % 24) * 128;
    int which = cb / 6;              // 0:q 1:k 2:v
    int c0l = (cb % 6) * 128;        // col base within 768
    int h = c0l >> 8, hd0 = c0l & 255;
    int bh = b_ * Hn + h;
    int wr = w >> 1, wc = w & 1;
    const u16* xp = xb + (size_t)r0*DIMn;
    const u16* wp = Wb + (size_t)(which*768 + c0l)*DIMn;
    const int sr = tid >> 3, ssg = tid & 7;     // staging: rows sr+32i, seg ssg

    u16x8 xreg[4], wreg[4];
    #pragma unroll
    for (int i = 0; i < 4; ++i) {
        xreg[i] = *(const u16x8*)(xp + (size_t)(sr + 32*i)*DIMn + ssg*8);
        wreg[i] = *(const u16x8*)(wp + (size_t)(sr + 32*i)*DIMn + ssg*8);
    }

    f32x4 acc[4][4];
    #pragma unroll
    for (int i = 0; i < 4; ++i)
        #pragma unroll
        for (int j = 0; j < 4; ++j) acc[i][j] = (f32x4){0.f,0.f,0.f,0.f};

    for (int k0 = 0; k0 < DIMn; k0 += 64) {
        int k0n = (k0 + 64 < DIMn) ? k0 + 64 : 0;
        __syncthreads();
        #pragma unroll
        for (int i = 0; i < 4; ++i) {
            *(u16x8*)&Xs[(sr + 32*i)*72 + ssg*8] = xreg[i];
            *(u16x8*)&Ws[(sr + 32*i)*72 + ssg*8] = wreg[i];
        }
        __syncthreads();
        #pragma unroll
        for (int i = 0; i < 4; ++i) {
            xreg[i] = *(const u16x8*)(xp + (size_t)(sr + 32*i)*DIMn + k0n + ssg*8);
            wreg[i] = *(const u16x8*)(wp + (size_t)(sr + 32*i)*DIMn + k0n + ssg*8);
        }
        #pragma unroll
        for (int ks = 0; ks < 2; ++ks) {
            bf16x8 af[4], bf[4];
            #pragma unroll
            for (int mt = 0; mt < 4; ++mt)
                af[mt] = ld_frag16(&Xs[(wr*64 + mt*16 + l15)*72 + ks*32 + quad*8]);
            #pragma unroll
            for (int nt = 0; nt < 4; ++nt)
                bf[nt] = ld_frag16(&Ws[(wc*64 + nt*16 + l15)*72 + ks*32 + quad*8]);
            #pragma unroll
            for (int mt = 0; mt < 4; ++mt)
                #pragma unroll
                for (int nt = 0; nt < 4; ++nt)
                    acc[mt][nt] = MFMA(af[mt], bf[nt], acc[mt][nt]);
        }
    }
    __syncthreads();   // last MFMA fragment reads done before Pool reuse
    // dump acc into this wave's 64x72 bounce region (transposed for v)
    u16* Cw = Pool + w*(64*72);
    if (which < 2) {
        #pragma unroll
        for (int mt = 0; mt < 4; ++mt)
            #pragma unroll
            for (int nt = 0; nt < 4; ++nt)
                #pragma unroll
                for (int r = 0; r < 4; ++r)
                    Cw[(mt*16 + quad*4 + r)*72 + nt*16 + l15] = f2bf(acc[mt][nt][r]);
    } else {
        #pragma unroll
        for (int mt = 0; mt < 4; ++mt)
            #pragma unroll
            for (int nt = 0; nt < 4; ++nt) {
                u16x4 pk;
                #pragma unroll
                for (int r = 0; r < 4; ++r) pk[r] = f2bf(acc[mt][nt][r]);
                *(u16x4*)&Cw[(nt*16 + l15)*72 + mt*16 + quad*4] = pk;
            }
    }
    __syncthreads();
    // cooperative coalesced global write: 128 rows x 16 u16x8 segs
    #pragma unroll
    for (int i = 0; i < 8; ++i) {
        int u = tid + i*256;
        int row = u >> 4, seg = u & 15;
        if (which < 2) {
            int wv = ((row >> 6) << 1) | (seg >> 3);   // wr = n-half, wc = hd-half
            u16x8 vv = *(const u16x8*)&Pool[wv*(64*72) + (row & 63)*72 + (seg & 7)*8];
            u16* dst = (which == 0) ? qh : kh;
            *(u16x8*)(dst + ((size_t)bh*Nn + n0 + row)*HDn + hd0 + seg*8) = vv;
        } else {
            int wv = ((seg >> 3) << 1) | (row >> 6);   // wr = n-half(seg), wc = hd-half(row)
            u16x8 vv = *(const u16x8*)&Pool[wv*(64*72) + (row & 63)*72 + (seg & 7)*8];
            *(u16x8*)(vT + ((size_t)bh*EP + hd0 + row)*Nn + n0 + seg*8) = vv;
        }
    }
}

// ---------------------------------------------------------------------------
// K1b: positional rows 256..261 of vT; rows 262..271 get zero.
// ---------------------------------------------------------------------------
__global__ void pos_fill(u16* __restrict__ vT) {
    int idx = blockIdx.x * blockDim.x + threadIdx.x;   // over BH*16*N
    int bh = idx / (16*Nn);
    int rem = idx - bh*16*Nn;
    int row = rem / Nn;        // 0..15
    int n = rem - row*Nn;
    int gy = n % 48, gx = n / 48;
    float p3 = -1.0f + (2.0f/47.0f)*gy;
    float p4 = -1.0f + (2.0f/63.0f)*gx;
    float v = 0.f;
    if (row == 0) v = p3*p3;
    else if (row == 1) v = p4*p4;
    else if (row == 2) v = p3*p4;
    else if (row == 3) v = p3;
    else if (row == 4) v = p4;
    else if (row == 5) v = 1.0f;
    vT[((size_t)bh*EP + 256 + row)*Nn + n] = f2bf(v);
}

// ---------------------------------------------------------------------------
// K2 (R22): rc with 2 n-tiles per block (n-tile 128). Rationale: rc is the
// largest aggregate item (~2x65-70us); per chunk the staging writes, 16 K
// ds_reads, and 2 barriers are per-CHUNK costs while MFMA+epilogue scale
// per-OUTPUT. Pairing two n-tiles: K chunk staged ONCE feeds 64 MFMA/wave
// with the SAME 16 ds_reads (4:1 vs 2:1); K staging traffic, ds_reads, and
// barriers per output halve. qf doubles (2-pass Q staging through Ks);
// epilogue (exp/P2/merge-net: per-output) runs twice. VGPR ~150 (3 w/SIMD).
// C slices: nb*4 + sn*2 + wn (still 96 -> inv unchanged).
// P2[nl][m] = bf16(exp(0.125*S)) in PV A-fragment layout (m-contig u16x4).
// ---------------------------------------------------------------------------
__global__ __launch_bounds__(256) void rc_mfma(const u16* __restrict__ qh,
                                               const u16* __restrict__ kh,
                                               float* __restrict__ R_part,
                                               float* __restrict__ C_part,
                                               u16* __restrict__ P2,
                                               int g0) {
    __shared__ u16 Ks[64*264];            // K chunk staging; Q bounce in prologue
    __shared__ float rbuf[2][2][2][64];   // [sn][wm][nt][wn*32 + l15]
    int tid = threadIdx.x;
    int w = tid >> 6, lane = tid & 63, quad = lane >> 4, l15 = lane & 15;
    // XCD-chunked remap (nwg = MSn*24*gbh, divisible by 8; ms fastest so the
    // 8 same-(nb,bhl) ms-blocks share one XCD's L2 for the Q tile)
    int nwg = (int)(gridDim.x * gridDim.y * gridDim.z);
    int lid = blockIdx.x + (int)gridDim.x*(blockIdx.y + (int)gridDim.y*blockIdx.z);
    int swz = (lid & 7)*(nwg >> 3) + (lid >> 3);
    int ms = swz % MSn;
    int rem_ = swz / MSn;
    int nb = rem_ % 24;
    int bhl = rem_ / 24;
    int bh = g0 + bhl;
    int n0 = nb * 128;
    int msBase = ms * (Nn/MSn);
    const u16* qp = qh + ((size_t)bh*Nn + n0)*HDn;
    const u16* kp = kh + (size_t)bh*Nn*HDn;
    u16* pw = P2 + (size_t)bhl*Nn*Nn;     // LOCAL bh slice
    int wm = w & 1, wn = w >> 1;

    // issue chunk-0 K prefetch early (global->reg; doesn't touch LDS)
    const int kr = tid >> 5, ksg = tid & 31;
    u16x8 kreg[8];
    #pragma unroll
    for (int i = 0; i < 8; ++i)
        kreg[i] = *(const u16x8*)(kp + (size_t)(msBase + kr + 8*i)*HDn + ksg*8);

    // Q staging: 2 passes of 64 rows through Ks; every wave reads both passes
    bf16x8 qf[2][2][8];        // [sn][nt][ks]
    #pragma unroll
    for (int p = 0; p < 2; ++p) {
        if (p) __syncthreads();    // qf[0] reads done before overwrite
        #pragma unroll
        for (int i = 0; i < 8; ++i) {
            int e = tid + i*256;
            int row = e >> 5, seg = e & 31;
            *(u16x8*)&Ks[row*264 + seg*8] =
                *(const u16x8*)(qp + (size_t)(p*64 + row)*HDn + seg*8);
        }
        __syncthreads();
        #pragma unroll
        for (int nt = 0; nt < 2; ++nt)
            #pragma unroll
            for (int ks = 0; ks < 8; ++ks)
                qf[p][nt][ks] = ld_frag16(&Ks[((2*wn+nt)*16 + l15)*264 + ks*32 + quad*8]);
    }
    // loop-head barrier protects qf[1] reads before K staging overwrites Ks

    float rAcc[2][2] = {{0.f,0.f},{0.f,0.f}};    // [sn][nt]
    const int NCH = Nn/(MSn*64);          // 6 chunks per slice
    for (int mc = 0; mc < NCH; ++mc) {
        int m0 = msBase + mc*64;
        int m0n = msBase + ((mc + 1 < NCH) ? (mc + 1)*64 : 0);
        __syncthreads();       // qf reads (mc=0) / previous MFMA reads done
        #pragma unroll
        for (int i = 0; i < 8; ++i)
            *(u16x8*)&Ks[(kr + 8*i)*264 + ksg*8] = kreg[i];
        __syncthreads();
        #pragma unroll
        for (int i = 0; i < 8; ++i)
            kreg[i] = *(const u16x8*)(kp + (size_t)(m0n + kr + 8*i)*HDn + ksg*8);
        f32x4 s0[2][2], s1[2][2];
        #pragma unroll
        for (int i = 0; i < 2; ++i)
            #pragma unroll
            for (int j = 0; j < 2; ++j) {
                s0[i][j] = (f32x4){0.f,0.f,0.f,0.f};
                s1[i][j] = (f32x4){0.f,0.f,0.f,0.f};
            }
        #pragma unroll
        for (int ks = 0; ks < 8; ++ks) {
            bf16x8 a0 = ld_frag16(&Ks[((2*wm+0)*16 + l15)*264 + ks*32 + quad*8]);
            bf16x8 a1 = ld_frag16(&Ks[((2*wm+1)*16 + l15)*264 + ks*32 + quad*8]);
            s0[0][0] = MFMA(a0, qf[0][0][ks], s0[0][0]);
            s0[0][1] = MFMA(a0, qf[0][1][ks], s0[0][1]);
            s0[1][0] = MFMA(a1, qf[0][0][ks], s0[1][0]);
            s0[1][1] = MFMA(a1, qf[0][1][ks], s0[1][1]);
            s1[0][0] = MFMA(a0, qf[1][0][ks], s1[0][0]);
            s1[0][1] = MFMA(a0, qf[1][1][ks], s1[0][1]);
            s1[1][0] = MFMA(a1, qf[1][0][ks], s1[1][0]);
            s1[1][1] = MFMA(a1, qf[1][1][ks], s1[1][1]);
        }
        // epilogue per sub-n-tile (per-output costs: exp, P2, R/C partials)
        #pragma unroll
        for (int sn = 0; sn < 2; ++sn) {
            float ex[2][2][4];
            #pragma unroll
            for (int mt = 0; mt < 2; ++mt)
                #pragma unroll
                for (int nt = 0; nt < 2; ++nt)
                    #pragma unroll
                    for (int r = 0; r < 4; ++r) {
                        float sv = sn ? s1[mt][nt][r] : s0[mt][nt][r];
                        ex[mt][nt][r] = __expf(0.0625f * sv);
                    }
            // P2 = ex^2 (== exp(0.125*S)), bf16, [n][m] with m-contig u16x4
            #pragma unroll
            for (int mt = 0; mt < 2; ++mt)
                #pragma unroll
                for (int nt = 0; nt < 2; ++nt) {
                    u16x4 pk;
                    #pragma unroll
                    for (int r = 0; r < 4; ++r) {
                        float e2 = ex[mt][nt][r];
                        pk[r] = f2bf(e2 * e2);
                    }
                    *(u16x4*)(pw + (size_t)(n0 + sn*64 + (2*wn+nt)*16 + l15)*Nn
                                 + m0 + (2*wm+mt)*16 + quad*4) = pk;
                }
            #pragma unroll
            for (int nt = 0; nt < 2; ++nt)
                #pragma unroll
                for (int mt = 0; mt < 2; ++mt)
                    #pragma unroll
                    for (int r = 0; r < 4; ++r) rAcc[sn][nt] += ex[mt][nt][r];
            // C partial via merge-network (8 bpermute for 8 values)
            {
                float v0 = ex[0][0][0] + ex[0][1][0];
                float v1 = ex[0][0][1] + ex[0][1][1];
                float v2 = ex[0][0][2] + ex[0][1][2];
                float v3 = ex[0][0][3] + ex[0][1][3];
                float v4 = ex[1][0][0] + ex[1][1][0];
                float v5 = ex[1][0][1] + ex[1][1][1];
                float v6 = ex[1][0][2] + ex[1][1][2];
                float v7 = ex[1][0][3] + ex[1][1][3];
                int b0 = l15 & 1, b1 = l15 & 2, b2 = l15 & 4;
                float u01 = (b0 ? v1 : v0) + __shfl_xor(b0 ? v0 : v1, 1, 16);
                float u23 = (b0 ? v3 : v2) + __shfl_xor(b0 ? v2 : v3, 1, 16);
                float u45 = (b0 ? v5 : v4) + __shfl_xor(b0 ? v4 : v5, 1, 16);
                float u67 = (b0 ? v7 : v6) + __shfl_xor(b0 ? v6 : v7, 1, 16);
                float t03 = (b1 ? u23 : u01) + __shfl_xor(b1 ? u01 : u23, 2, 16);
                float t47 = (b1 ? u67 : u45) + __shfl_xor(b1 ? u45 : u67, 2, 16);
                float s07 = (b2 ? t47 : t03) + __shfl_xor(b2 ? t03 : t47, 4, 16);
                s07 += __shfl_xor(s07, 8, 16);
                if (l15 < 8) {
                    float* cpart = C_part
                        + ((size_t)(nb*4 + sn*2 + wn)*BHn + bh)*Nn;
                    cpart[m0 + (2*wm + (l15 >> 2))*16 + quad*4 + (l15 & 3)] = s07;
                }
            }
        }
    }
    // R: shfl reduces quad; cross-wm combine via LDS; wm==0 writes the slot.
    #pragma unroll
    for (int sn = 0; sn < 2; ++sn)
        #pragma unroll
        for (int nt = 0; nt < 2; ++nt) {
            float rp = rAcc[sn][nt];
            rp += __shfl_xor(rp, 16, 64);
            rp += __shfl_xor(rp, 32, 64);
            if (quad == 0) rbuf[sn][wm][nt][wn*32 + l15] = rp;
        }
    __syncthreads();
    #pragma unroll
    for (int sn = 0; sn < 2; ++sn)
        #pragma unroll
        for (int nt = 0; nt < 2; ++nt) {
            if (quad == 0 && wm == 0) {
                float tot = rbuf[sn][0][nt][wn*32 + l15] + rbuf[sn][1][nt][wn*32 + l15];
                R_part[(size_t)ms*BHn*Nn + (size_t)bh*Nn
                       + n0 + sn*64 + (2*wn+nt)*16 + l15] = tot;
            }
        }
}

// ---------------------------------------------------------------------------
// K2b: per-group inverse sums. Pointers pre-offset by g0*Nn; i spans gbh*Nn.
// ---------------------------------------------------------------------------
__global__ void inv_kernel(const float* __restrict__ Rg,
                           const float* __restrict__ Cg,
                           float* __restrict__ iRg, float* __restrict__ iCg) {
    int i = blockIdx.x * blockDim.x + threadIdx.x;
    float r = 0.f;
    #pragma unroll
    for (int s = 0; s < MSn; ++s)
        r += Rg[(size_t)s*BHn*Nn + i];
    float c = 0.f;
    for (int s = 0; s < 96; ++s)
        c += Cg[(size_t)s*BHn*Nn + i];
    iRg[i] = 1.0f / r;
    iCg[i] = 1.0f / c;
}

// ---------------------------------------------------------------------------
// K2c: vTs[bhl][e][m] = vT[bh][e][m] * iC[bh][m] for the group's bh slice.
// ---------------------------------------------------------------------------
__global__ void scale_v(const u16* __restrict__ vTg, const float* __restrict__ iCg,
                        u16* __restrict__ vTs) {
    int idx = blockIdx.x * blockDim.x + threadIdx.x;   // gbh*EP*Nn/8 threads
    int bhl = idx / (EP*Nn/8);
    int rem = idx - bhl*(EP*Nn/8);
    size_t off = (size_t)bhl*EP*Nn + (size_t)rem*8;
    int m = (rem % (Nn/8)) * 8;
    u16x8 v = *(const u16x8*)(vTg + off);
    float4 c0 = *(const float4*)(iCg + (size_t)bhl*Nn + m);
    float4 c1 = *(const float4*)(iCg + (size_t)bhl*Nn + m + 4);
    u16x8 o;
    o[0]=f2bf(bf2f(v[0])*c0.x); o[1]=f2bf(bf2f(v[1])*c0.y);
    o[2]=f2bf(bf2f(v[2])*c0.z); o[3]=f2bf(bf2f(v[3])*c0.w);
    o[4]=f2bf(bf2f(v[4])*c1.x); o[5]=f2bf(bf2f(v[5])*c1.y);
    o[6]=f2bf(bf2f(v[6])*c1.z); o[7]=f2bf(bf2f(v[7])*c1.w);
    *(u16x8*)(vTs + off) = o;
}

// ---------------------------------------------------------------------------
// K3 (R21): pure PV GEMM, z-split with LEAN V staging + XCD swizzle.
//   f1aT[e][n] = iR[n] * sum_m P2[n][m] * vTs[e][m]
// ---------------------------------------------------------------------------
__global__ __launch_bounds__(256, 4) void pv_mfma(const u16* __restrict__ P2,
                                                  const u16* __restrict__ vTs,
                                                  const float* __restrict__ iRg,
                                                  u16* __restrict__ f1aTg) {
    __shared__ u16 Ps2[64*72];    //  9216 B  (P chunk, rows n, pad->72)
    __shared__ u16 Vt[144*72];    // 20736 B  (this z-half's V rows, pad->72)
    int tid = threadIdx.x;
    int w = tid >> 6, lane = tid & 63, quad = lane >> 4, l15 = lane & 15;
    // XCD-chunked remap (nwg = 48*gbh*2, divisible by 8)
    int nwg = (int)(gridDim.x * gridDim.y * gridDim.z);
    int lid = blockIdx.x + (int)gridDim.x*(blockIdx.y + (int)gridDim.y*blockIdx.z);
    int swz = (lid & 7)*(nwg >> 3) + (lid >> 3);
    int n0b = swz % 48;
    int rem_ = swz / 48;
    int bhl = rem_ % (int)gridDim.y;
    int z = rem_ / (int)gridDim.y;     // 0: e-tiles 0..7; 1: e-tiles 8..16
    int n0 = n0b * 64;
    const u16* pp = P2  + ((size_t)bhl*Nn + n0)*Nn;
    const u16* vp = vTs + (size_t)bhl*EP*Nn + (size_t)(z*128)*Nn;  // z-half base
    const int sr = tid >> 3, sg = tid & 7;     // staging: rows sr+32i, seg sg
    u16x8 preg[2], vreg[5];
    // prefetch chunk 0 (V: 128 rows for z=0, 144 for z=1)
    #pragma unroll
    for (int i = 0; i < 2; ++i)
        preg[i] = *(const u16x8*)(pp + (size_t)(sr + 32*i)*Nn + sg*8);
    #pragma unroll
    for (int i = 0; i < 5; ++i)
        if (i < 4 || (z == 1 && tid < 128))
            vreg[i] = *(const u16x8*)(vp + (size_t)(sr + 32*i)*Nn + sg*8);

    f32x4 acc[4][3];
    #pragma unroll
    for (int a = 0; a < 4; ++a)
        #pragma unroll
        for (int b = 0; b < 3; ++b) acc[a][b] = (f32x4){0.f,0.f,0.f,0.f};

    for (int mc = 0; mc < Nn/64; ++mc) {
        int m0n = (mc + 1 < Nn/64) ? (mc + 1)*64 : 0;   // clamped next chunk
        __syncthreads();   // previous chunk's LDS readers done
        #pragma unroll
        for (int i = 0; i < 2; ++i)
            *(u16x8*)&Ps2[(sr + 32*i)*72 + sg*8] = preg[i];
        #pragma unroll
        for (int i = 0; i < 5; ++i)
            if (i < 4 || (z == 1 && tid < 128))
                *(u16x8*)&Vt[(sr + 32*i)*72 + sg*8] = vreg[i];
        __syncthreads();
        // issue prefetch for next chunk (overlaps MFMA below)
        #pragma unroll
        for (int i = 0; i < 2; ++i)
            preg[i] = *(const u16x8*)(pp + (size_t)(sr + 32*i)*Nn + m0n + sg*8);
        #pragma unroll
        for (int i = 0; i < 5; ++i)
            if (i < 4 || (z == 1 && tid < 128))
                vreg[i] = *(const u16x8*)(vp + (size_t)(sr + 32*i)*Nn + m0n + sg*8);
        // acc += P2 · vTs^T   (A = Ps2[n][m], B = Vt[e_local][m])
        #pragma unroll
        for (int ks = 0; ks < 2; ++ks) {
            bf16x8 pa[4];
            #pragma unroll
            for (int nt = 0; nt < 4; ++nt)
                pa[nt] = ld_frag16(&Ps2[(nt*16 + l15)*72 + ks*32 + quad*8]);
            #pragma unroll
            for (int et = 0; et < 3; ++et) {
                const int lt = (et < 2) ? (w*2 + et) : 8;   // local tile in Vt
                const bool act = (et < 2 || (z == 1 && w == 3));
                if (act) {   // wave-uniform; static indices
                    bf16x8 vb = ld_frag16(&Vt[(lt*16 + l15)*72 + ks*32 + quad*8]);
                    #pragma unroll
                    for (int nt = 0; nt < 4; ++nt)
                        acc[nt][et] = MFMA(pa[nt], vb, acc[nt][et]);
                }
            }
        }
    }
    // epilogue: scale by invR[n], pack bf16, store transposed f1aT[e][n]
    #pragma unroll
    for (int nt = 0; nt < 4; ++nt) {
        float4 ir4 = *(const float4*)(iRg + (size_t)bhl*Nn + n0 + nt*16 + quad*4);
        #pragma unroll
        for (int et = 0; et < 3; ++et) {
            const int tile = (et < 2) ? (z*8 + w*2 + et) : 16;
            const bool act = (et < 2 || (z == 1 && w == 3));
            if (act) {
                int e = tile*16 + l15;
                u16x4 ov;
                #pragma unroll
                for (int r = 0; r < 4; ++r)
                    ov[r] = f2bf(acc[nt][et][r] * ((const float*)&ir4)[r]);
                *(u16x4*)(f1aTg + ((size_t)bhl*EP + e)*Nn + n0 + nt*16 + quad*4) = ov;
            }
        }
    }
}

// ---------------------------------------------------------------------------
// K4 (R21): fund_part[ks][bh][d][e] = sum_{n in ks-slice} vT[d][n]*f1aT[e][n].
// Register-prefetch double-stage + K-split KSn=4 (1200 blocks) + XCD swizzle.
// ---------------------------------------------------------------------------
__global__ __launch_bounds__(256) void fund_mfma(const u16* __restrict__ vT,
                                                 const u16* __restrict__ f1aT,
                                                 float* __restrict__ fund_part) {
    __shared__ u16 At[64*136];
    __shared__ u16 Bt[64*136];
    int tid = threadIdx.x;
    int w = tid >> 6, lane = tid & 63, quad = lane >> 4, l15 = lane & 15;
    // XCD-chunked remap (nwg = 5*5*48 = 1200, divisible by 8)
    int lid = blockIdx.x + 5*(blockIdx.y + 5*blockIdx.z);
    int swz = (lid & 7)*150 + (lid >> 3);
    int ex_ = swz % 5;
    int rem_ = swz / 5;
    int dx_ = rem_ % 5;
    int bz = rem_ / 5;
    int bh = bz >> 2;            // KSn = 4
    int ks = bz & 3;
    int d0 = dx_ * 64, e0 = ex_ * 64;
    const u16* ap = vT   + (size_t)bh*EP*Nn;
    const u16* bp = f1aT + (size_t)bh*EP*Nn;
    int wd = w & 1, we = w >> 1;
    const u16x8 zero8 = {0,0,0,0,0,0,0,0};
    const int nc0 = ks * (Nn/KSn);          // 768-wide K slice
    const int NCH = (Nn/KSn)/128;           // 6 chunks

    const int srow = tid >> 4, seg = tid & 15;   // staging rows srow+16i
    u16x8 areg[4], breg[4];
    #pragma unroll
    for (int i = 0; i < 4; ++i) {
        int row = srow + 16*i;
        int da = d0 + row, eb = e0 + row;
        areg[i] = (da < EP) ? *(const u16x8*)(ap + (size_t)da*Nn + nc0 + seg*8) : zero8;
        breg[i] = (eb < EP) ? *(const u16x8*)(bp + (size_t)eb*Nn + nc0 + seg*8) : zero8;
    }

    f32x4 acc[2][2];
    #pragma unroll
    for (int i = 0; i < 2; ++i)
        #pragma unroll
        for (int j = 0; j < 2; ++j) acc[i][j] = (f32x4){0.f,0.f,0.f,0.f};

    for (int mc = 0; mc < NCH; ++mc) {
        int ncn = nc0 + ((mc + 1 < NCH) ? (mc + 1)*128 : 0);
        __syncthreads();
        #pragma unroll
        for (int i = 0; i < 4; ++i) {
            int row = srow + 16*i;
            *(u16x8*)&At[row*136 + seg*8] = areg[i];
            *(u16x8*)&Bt[row*136 + seg*8] = breg[i];
        }
        __syncthreads();
        #pragma unroll
        for (int i = 0; i < 4; ++i) {
            int row = srow + 16*i;
            int da = d0 + row, eb = e0 + row;
            areg[i] = (da < EP) ? *(const u16x8*)(ap + (size_t)da*Nn + ncn + seg*8) : zero8;
            breg[i] = (eb < EP) ? *(const u16x8*)(bp + (size_t)eb*Nn + ncn + seg*8) : zero8;
        }
        #pragma unroll
        for (int kk = 0; kk < 4; ++kk) {
            bf16x8 a0 = ld_frag16(&At[((2*wd+0)*16 + l15)*136 + kk*32 + quad*8]);
            bf16x8 a1 = ld_frag16(&At[((2*wd+1)*16 + l15)*136 + kk*32 + quad*8]);
            bf16x8 b0 = ld_frag16(&Bt[((2*we+0)*16 + l15)*136 + kk*32 + quad*8]);
            bf16x8 b1 = ld_frag16(&Bt[((2*we+1)*16 + l15)*136 + kk*32 + quad*8]);
            acc[0][0] = MFMA(a0, b0, acc[0][0]);
            acc[0][1] = MFMA(a0, b1, acc[0][1]);
            acc[1][0] = MFMA(a1, b0, acc[1][0]);
            acc[1][1] = MFMA(a1, b1, acc[1][1]);
        }
    }
    float* fp = fund_part + (size_t)(ks*BHn + bh)*Dn*FP;
    #pragma unroll
    for (int dt = 0; dt < 2; ++dt)
        #pragma unroll
        for (int et = 0; et < 2; ++et)
            #pragma unroll
            for (int r = 0; r < 4; ++r) {
                int d = d0 + (2*wd+dt)*16 + quad*4 + r;
                int e = e0 + (2*we+et)*16 + l15;
                if (d < Dn && e < Dn)
                    fp[(size_t)d*FP + e] = acc[dt][et][r];
            }
}

// ---------------------------------------------------------------------------
// K5 (R19): out[b,d2,o] = sum_j (sum_ks fund_part[ks])[...] * WpfT[j][o]+bpf
// ---------------------------------------------------------------------------
__device__ __forceinline__ float4 ld4sum(const float* p, size_t SL) {
    float4 a = *(const float4*)p;
    float4 b = *(const float4*)(p + SL);
    float4 c = *(const float4*)(p + 2*SL);
    float4 d = *(const float4*)(p + 3*SL);
    return (float4){a.x+b.x+c.x+d.x, a.y+b.y+c.y+d.y,
                    a.z+b.z+c.z+d.z, a.w+b.w+c.w+d.w};
}

__global__ __launch_bounds__(256) void out_gemm(const float* __restrict__ fund_part,
                                                const float* __restrict__ WpfT,
                                                const float* __restrict__ bpf,
                                                float* __restrict__ out) {
    __shared__ float As[2][16][68];
    __shared__ float Bs[2][16][68];
    const size_t SL = (size_t)BHn*Dn*FP;   // ks-slice stride (floats)
    int tid = threadIdx.x;
    int b_ = blockIdx.z;
    int d2b = blockIdx.y * 64, ob = blockIdx.x * 64;
    int ty = tid >> 4, tx = tid & 15;      // 4x4 outputs at (d2b+ty*4, ob+tx*4)
    int srow = tid >> 4, sc4 = (tid & 15) * 4;   // staging: j row, 4-col seg
    const int NIT = (786 + 15) / 16;       // 50

    float4 aReg, bReg;
    {   // chunk 0
        int j = srow;
        int h = j / Dn, d1 = j - h*Dn;
        const float* srcA = fund_part + ((size_t)(b_*Hn + h)*Dn + d1)*FP + d2b + sc4;
        if (d2b + sc4 + 3 < Dn) aReg = ld4sum(srcA, SL);
        else {
            float t[4] = {0.f,0.f,0.f,0.f};
            for (int u2 = 0; u2 < 4; ++u2)
                if (d2b + sc4 + u2 < Dn)
                    t[u2] = srcA[u2] + srcA[u2+SL] + srcA[u2+2*SL] + srcA[u2+3*SL];
            aReg = (float4){t[0],t[1],t[2],t[3]};
        }
        bReg = *(const float4*)(WpfT + (size_t)j*768 + ob + sc4);
    }
    *(float4*)&As[0][srow][sc4] = aReg;
    *(float4*)&Bs[0][srow][sc4] = bReg;
    __syncthreads();

    float acc[4][4] = {};
    for (int c = 0; c < NIT; ++c) {
        int buf = c & 1;
        if (c + 1 < NIT) {   // prefetch next chunk (global -> regs)
            int j = (c + 1)*16 + srow;
            aReg = (float4){0.f,0.f,0.f,0.f};
            bReg = (float4){0.f,0.f,0.f,0.f};
            if (j < 786) {
                int h = j / Dn, d1 = j - h*Dn;
                const float* srcA = fund_part + ((size_t)(b_*Hn + h)*Dn + d1)*FP + d2b + sc4;
                if (d2b + sc4 + 3 < Dn) aReg = ld4sum(srcA, SL);
                else {
                    float t[4] = {0.f,0.f,0.f,0.f};
                    for (int u2 = 0; u2 < 4; ++u2)
                        if (d2b + sc4 + u2 < Dn)
                            t[u2] = srcA[u2] + srcA[u2+SL] + srcA[u2+2*SL] + srcA[u2+3*SL];
                    aReg = (float4){t[0],t[1],t[2],t[3]};
                }
                bReg = *(const float4*)(WpfT + (size_t)j*768 + ob + sc4);
            }
        }
        #pragma unroll
        for (int kk = 0; kk < 16; ++kk) {
            float4 a = *(const float4*)&As[buf][kk][ty*4];
            float4 b = *(const float4*)&Bs[buf][kk][tx*4];
            acc[0][0] += a.x*b.x; acc[0][1] += a.x*b.y; acc[0][2] += a.x*b.z; acc[0][3] += a.x*b.w;
            acc[1][0] += a.y*b.x; acc[1][1] += a.y*b.y; acc[1][2] += a.y*b.z; acc[1][3] += a.y*b.w;
            acc[2][0] += a.z*b.x; acc[2][1] += a.z*b.y; acc[2][2] += a.z*b.z; acc[2][3] += a.z*b.w;
            acc[3][0] += a.w*b.x; acc[3][1] += a.w*b.y; acc[3][2] += a.w*b.z; acc[3][3] += a.w*b.w;
        }
        if (c + 1 < NIT) {
            *(float4*)&As[buf^1][srow][sc4] = aReg;
            *(float4*)&Bs[buf^1][srow][sc4] = bReg;
            __syncthreads();
        }
    }
    #pragma unroll
    for (int i = 0; i < 4; ++i) {
        int d2 = d2b + ty*4 + i;
        if (d2 >= Dn) continue;
        #pragma unroll
        for (int j = 0; j < 4; ++j) {
            int o = ob + tx*4 + j;
            out[((size_t)b_*Dn + d2)*DIMn + o] = acc[i][j] + bpf[o];
        }
    }
}

// ---------------------------------------------------------------------------
// Workspace (ws_size-adaptive):
//   fixed region (~108 MB): qh kh vT f1aT Cp iR iC fund_part(KSn slices) WpfT
//   region2 = max(xb+Wb staging [22.4 MB], gbh*(P2+vTs) + Rp)
//   gbh = largest of {12,6,4,3,2,1} that fits ws_size.
// ---------------------------------------------------------------------------
extern "C" void kernel_launch(void* const* d_in, const int* in_sizes, int n_in,
                              void* d_out, int out_size, void* d_ws, size_t ws_size,
                              hipStream_t stream) {
    const float* x    = (const float*)d_in[0];   // [4,3072,768]
    const float* Wqkv = (const float*)d_in[1];   // [2304,768]
    const float* Wpf  = (const float*)d_in[2];   // [768,786]
    const float* bpf  = (const float*)d_in[3];   // [768]
    float* out = (float*)d_out;                  // [4,262,768]

    char* p = (char*)d_ws;
    u16* qh    = (u16*)p;                       p += (size_t)BHn*Nn*HDn*2;   // 18.87 MB
    u16* kh    = (u16*)p;                       p += (size_t)BHn*Nn*HDn*2;   // 18.87 MB
    u16* vT    = (u16*)p;                       p += (size_t)BHn*EP*Nn*2;    // 20.05 MB
    u16* f1aT  = (u16*)p;                       p += (size_t)BHn*EP*Nn*2;    // 20.05 MB
    float* Cp  = (float*)p;                     p += (size_t)96*BHn*Nn*4;    // 14.16 MB
    float* iR  = (float*)p;                     p += (size_t)BHn*Nn*4;
    float* iC  = (float*)p;                     p += (size_t)BHn*Nn*4;
    float* fund= (float*)p;                     p += (size_t)KSn*BHn*Dn*FP*4 + 256; // 13.3 MB
    float* WpfT= (float*)p;                     p += (size_t)786*768*4;      // 2.41 MB
    char* region2 = p;
    size_t fixedB = (size_t)(region2 - (char*)d_ws);
    size_t avail = (ws_size > fixedB) ? (ws_size - fixedB) : 0;

    const size_t perBh = ((size_t)Nn*Nn + (size_t)EP*Nn) * 2;   // 20,545,536
    const size_t rpB   = (size_t)MSn*BHn*Nn*4;                  //  1,179,648
    int gbh = 1;
    const int cand[5] = {12, 6, 4, 3, 2};
    for (int ci = 0; ci < 5; ++ci) {
        if ((size_t)cand[ci]*perBh + rpB <= avail) { gbh = cand[ci]; break; }
    }

    // qkv staging view of region2 (dead after qkv_mfma)
    u16* xb = (u16*)region2;
    u16* Wb = xb + (size_t)Bn*Nn*DIMn;
    // group-pipeline view of region2 (live from rc_mfma on)
    u16* P2  = (u16*)region2;
    u16* vTs = P2 + (size_t)gbh*Nn*Nn;
    float* Rp = (float*)(vTs + (size_t)gbh*EP*Nn);

    to_bf16  <<<dim3((Bn*Nn*DIMn/8 + 255)/256), 256, 0, stream>>>(x, xb, Bn*Nn*DIMn/8);
    to_bf16  <<<dim3((3*DIMn*DIMn/8 + 255)/256), 256, 0, stream>>>(Wqkv, Wb, 3*DIMn*DIMn/8);
    transpose_wpf<<<dim3(25, 24), 256, 0, stream>>>(Wpf, WpfT);
    qkv_mfma <<<dim3(18, 96), 256, 0, stream>>>(xb, Wb, qh, kh, vT);
    pos_fill <<<dim3(BHn*16*Nn/256), 256, 0, stream>>>(vT);

    for (int g0 = 0; g0 < BHn; g0 += gbh) {
        rc_mfma  <<<dim3(MSn, Nn/128, gbh), 256, 0, stream>>>(qh, kh, Rp, Cp, P2, g0);
        inv_kernel<<<dim3(gbh*Nn/256), 256, 0, stream>>>(
            Rp + (size_t)g0*Nn, Cp + (size_t)g0*Nn, iR + (size_t)g0*Nn, iC + (size_t)g0*Nn);
        scale_v  <<<dim3(gbh*EP*Nn/8/256), 256, 0, stream>>>(
            vT + (size_t)g0*EP*Nn, iC + (size_t)g0*Nn, vTs);
        pv_mfma  <<<dim3(Nn/64, gbh, 2), 256, 0, stream>>>(
            P2, vTs, iR + (size_t)g0*Nn, f1aT + (size_t)g0*EP*Nn);
    }

    fund_mfma<<<dim3(5, 5, BHn*KSn), 256, 0, stream>>>(vT, f1aT, fund);
    out_gemm <<<dim3(DIMn/64, 5, Bn), 256, 0, stream>>>(fund, WpfT, bpf, out);
}

// Round 13
// 497.082 us; speedup vs baseline: 1.0698x; 1.0698x over previous
//
#include <hip/hip_runtime.h>

typedef unsigned short u16;
typedef u16 u16x8 __attribute__((ext_vector_type(8)));
typedef u16 u16x4 __attribute__((ext_vector_type(4)));
typedef __bf16 bf16x8 __attribute__((ext_vector_type(8)));
typedef float f32x4 __attribute__((ext_vector_type(4)));

#define Bn   4
#define Nn   3072
#define DIMn 768
#define Hn   3
#define HDn  256
#define BHn  12
#define Dn   262
#define EP   272      // e-rows padded to 17*16
#define MSn  8        // rc m-slices
#define FP   264      // fund e-pitch (262 padded to 4-float multiple)
#define KSn  4        // fund K-split: 300 -> 1200 blocks

__device__ __forceinline__ u16 f2bf(float f) {
    unsigned u = __builtin_bit_cast(unsigned, f);
    u += 0x7fffu + ((u >> 16) & 1u);
    return (u16)(u >> 16);
}
__device__ __forceinline__ float bf2f(u16 h) {
    unsigned u = ((unsigned)h) << 16;
    return __builtin_bit_cast(float, u);
}
__device__ __forceinline__ bf16x8 ld_frag16(const u16* p) {   // 16B-aligned read
    return *(const bf16x8*)p;
}
#define MFMA(a,b,c) __builtin_amdgcn_mfma_f32_16x16x32_bf16(a, b, c, 0, 0, 0)

// ---------------------------------------------------------------------------
// K0: fp32 -> bf16 elementwise (x and W pre-conversion)
// ---------------------------------------------------------------------------
__global__ void to_bf16(const float* __restrict__ in, u16* __restrict__ out, int n8) {
    int i = blockIdx.x * blockDim.x + threadIdx.x;
    if (i >= n8) return;
    float4 a = *(const float4*)(in + (size_t)i*8);
    float4 b = *(const float4*)(in + (size_t)i*8 + 4);
    u16x8 o;
    o[0]=f2bf(a.x); o[1]=f2bf(a.y); o[2]=f2bf(a.z); o[3]=f2bf(a.w);
    o[4]=f2bf(b.x); o[5]=f2bf(b.y); o[6]=f2bf(b.z); o[7]=f2bf(b.w);
    *(u16x8*)(out + (size_t)i*8) = o;
}

// ---------------------------------------------------------------------------
// K0b: WpfT[j][o] = Wpf[o][j]  (fp32, LDS-bounce transpose).
// ---------------------------------------------------------------------------
__global__ __launch_bounds__(256) void transpose_wpf(const float* __restrict__ Wpf,
                                                     float* __restrict__ WpfT) {
    __shared__ float tile[32][33];
    int jt = blockIdx.x * 32;   // 25 tiles over 786
    int ot = blockIdx.y * 32;   // 24 tiles over 768
    int tx = threadIdx.x & 31, ty = threadIdx.x >> 5;   // ty 0..7
    #pragma unroll
    for (int k = 0; k < 4; ++k) {
        int o = ot + ty + 8*k;
        int j = jt + tx;
        tile[ty + 8*k][tx] = (j < 786) ? Wpf[(size_t)o*786 + j] : 0.0f;
    }
    __syncthreads();
    #pragma unroll
    for (int k = 0; k < 4; ++k) {
        int j = jt + ty + 8*k;
        if (j < 786) WpfT[(size_t)j*768 + ot + tx] = tile[tx][ty + 8*k];
    }
}

// ---------------------------------------------------------------------------
// K1 (R21): qkv = x @ W_qkv^T, 128x128 tile, 4x4 acc/wave, reg-prefetch
// staging, XCD-chunked swizzle. Closed branch: gll/LDS-swizzle (R20) and
// fetch reduction (R21) both left dur at ~73.5us — 2-barrier ceiling.
// Writes qh/kh bf16 [bh][n][256] and vT bf16 [bh][272][3072] (transposed).
// ---------------------------------------------------------------------------
__global__ __launch_bounds__(256) void qkv_mfma(const u16* __restrict__ xb,
                                                const u16* __restrict__ Wb,
                                                u16* __restrict__ qh,
                                                u16* __restrict__ kh,
                                                u16* __restrict__ vT) {
    __shared__ u16 Pool[2*128*72];          // Xs | Ws; reused as C bounce
    u16* Xs = Pool;
    u16* Ws = Pool + 128*72;
    int tid = threadIdx.x;
    int w = tid >> 6, lane = tid & 63, quad = lane >> 4, l15 = lane & 15;
    // XCD-chunked remap: hw linear id -> contiguous work range per XCD
    int lid = blockIdx.x + 18*blockIdx.y;           // nwg = 1728
    int swz = (lid & 7)*216 + (lid >> 3);
    int cb = swz % 18, rb = swz / 18;
    int r0 = rb * 128;
    int b_ = rb / 24;
    int n0 = (rb % 24) * 128;
    int which = cb / 6;              // 0:q 1:k 2:v
    int c0l = (cb % 6) * 128;        // col base within 768
    int h = c0l >> 8, hd0 = c0l & 255;
    int bh = b_ * Hn + h;
    int wr = w >> 1, wc = w & 1;
    const u16* xp = xb + (size_t)r0*DIMn;
    const u16* wp = Wb + (size_t)(which*768 + c0l)*DIMn;
    const int sr = tid >> 3, ssg = tid & 7;     // staging: rows sr+32i, seg ssg

    u16x8 xreg[4], wreg[4];
    #pragma unroll
    for (int i = 0; i < 4; ++i) {
        xreg[i] = *(const u16x8*)(xp + (size_t)(sr + 32*i)*DIMn + ssg*8);
        wreg[i] = *(const u16x8*)(wp + (size_t)(sr + 32*i)*DIMn + ssg*8);
    }

    f32x4 acc[4][4];
    #pragma unroll
    for (int i = 0; i < 4; ++i)
        #pragma unroll
        for (int j = 0; j < 4; ++j) acc[i][j] = (f32x4){0.f,0.f,0.f,0.f};

    for (int k0 = 0; k0 < DIMn; k0 += 64) {
        int k0n = (k0 + 64 < DIMn) ? k0 + 64 : 0;
        __syncthreads();
        #pragma unroll
        for (int i = 0; i < 4; ++i) {
            *(u16x8*)&Xs[(sr + 32*i)*72 + ssg*8] = xreg[i];
            *(u16x8*)&Ws[(sr + 32*i)*72 + ssg*8] = wreg[i];
        }
        __syncthreads();
        #pragma unroll
        for (int i = 0; i < 4; ++i) {
            xreg[i] = *(const u16x8*)(xp + (size_t)(sr + 32*i)*DIMn + k0n + ssg*8);
            wreg[i] = *(const u16x8*)(wp + (size_t)(sr + 32*i)*DIMn + k0n + ssg*8);
        }
        #pragma unroll
        for (int ks = 0; ks < 2; ++ks) {
            bf16x8 af[4], bf[4];
            #pragma unroll
            for (int mt = 0; mt < 4; ++mt)
                af[mt] = ld_frag16(&Xs[(wr*64 + mt*16 + l15)*72 + ks*32 + quad*8]);
            #pragma unroll
            for (int nt = 0; nt < 4; ++nt)
                bf[nt] = ld_frag16(&Ws[(wc*64 + nt*16 + l15)*72 + ks*32 + quad*8]);
            #pragma unroll
            for (int mt = 0; mt < 4; ++mt)
                #pragma unroll
                for (int nt = 0; nt < 4; ++nt)
                    acc[mt][nt] = MFMA(af[mt], bf[nt], acc[mt][nt]);
        }
    }
    __syncthreads();   // last MFMA fragment reads done before Pool reuse
    // dump acc into this wave's 64x72 bounce region (transposed for v)
    u16* Cw = Pool + w*(64*72);
    if (which < 2) {
        #pragma unroll
        for (int mt = 0; mt < 4; ++mt)
            #pragma unroll
            for (int nt = 0; nt < 4; ++nt)
                #pragma unroll
                for (int r = 0; r < 4; ++r)
                    Cw[(mt*16 + quad*4 + r)*72 + nt*16 + l15] = f2bf(acc[mt][nt][r]);
    } else {
        #pragma unroll
        for (int mt = 0; mt < 4; ++mt)
            #pragma unroll
            for (int nt = 0; nt < 4; ++nt) {
                u16x4 pk;
                #pragma unroll
                for (int r = 0; r < 4; ++r) pk[r] = f2bf(acc[mt][nt][r]);
                *(u16x4*)&Cw[(nt*16 + l15)*72 + mt*16 + quad*4] = pk;
            }
    }
    __syncthreads();
    // cooperative coalesced global write: 128 rows x 16 u16x8 segs
    #pragma unroll
    for (int i = 0; i < 8; ++i) {
        int u = tid + i*256;
        int row = u >> 4, seg = u & 15;
        if (which < 2) {
            int wv = ((row >> 6) << 1) | (seg >> 3);   // wr = n-half, wc = hd-half
            u16x8 vv = *(const u16x8*)&Pool[wv*(64*72) + (row & 63)*72 + (seg & 7)*8];
            u16* dst = (which == 0) ? qh : kh;
            *(u16x8*)(dst + ((size_t)bh*Nn + n0 + row)*HDn + hd0 + seg*8) = vv;
        } else {
            int wv = ((seg >> 3) << 1) | (row >> 6);   // wr = n-half(seg), wc = hd-half(row)
            u16x8 vv = *(const u16x8*)&Pool[wv*(64*72) + (row & 63)*72 + (seg & 7)*8];
            *(u16x8*)(vT + ((size_t)bh*EP + hd0 + row)*Nn + n0 + seg*8) = vv;
        }
    }
}

// ---------------------------------------------------------------------------
// K1b: positional rows 256..261 of vT; rows 262..271 get zero.
// ---------------------------------------------------------------------------
__global__ void pos_fill(u16* __restrict__ vT) {
    int idx = blockIdx.x * blockDim.x + threadIdx.x;   // over BH*16*N
    int bh = idx / (16*Nn);
    int rem = idx - bh*16*Nn;
    int row = rem / Nn;        // 0..15
    int n = rem - row*Nn;
    int gy = n % 48, gx = n / 48;
    float p3 = -1.0f + (2.0f/47.0f)*gy;
    float p4 = -1.0f + (2.0f/63.0f)*gx;
    float v = 0.f;
    if (row == 0) v = p3*p3;
    else if (row == 1) v = p4*p4;
    else if (row == 2) v = p3*p4;
    else if (row == 3) v = p3;
    else if (row == 4) v = p4;
    else if (row == 5) v = 1.0f;
    vT[((size_t)bh*EP + 256 + row)*Nn + n] = f2bf(v);
}

// ---------------------------------------------------------------------------
// K2 (R23 = R21 revert): rc, single 64-n-tile, merge-network C reduce, XCD
// swizzle. R22 post-mortem: 2-n-tile pairing regressed (83.4 vs ~66us) —
// VGPR 88->144 collapsed occupancy 19.7->9.5%, and rc's barrier-synced
// critical path lost more latency-hiding than staging amortization gained
// (FETCH did drop 42.6->33.5MB as designed). rc's per-thread state is
// occupancy-critical: pairing branch CLOSED (both directions now: R16 wider
// block, R22 wider per-block work).
// P2[nl][m] = bf16(exp(0.125*S)) in PV A-fragment layout (m-contig u16x4).
// ---------------------------------------------------------------------------
__global__ __launch_bounds__(256) void rc_mfma(const u16* __restrict__ qh,
                                               const u16* __restrict__ kh,
                                               float* __restrict__ R_part,
                                               float* __restrict__ C_part,
                                               u16* __restrict__ P2,
                                               int g0) {
    __shared__ u16 Ks[64*264];            // doubles as Q staging during preload
    __shared__ float rbuf[2][2][64];      // [wm][nt][wn*32 + l15]
    int tid = threadIdx.x;
    int w = tid >> 6, lane = tid & 63, quad = lane >> 4, l15 = lane & 15;
    // XCD-chunked remap (nwg = 8*48*gbh, divisible by 8)
    int nwg = (int)(gridDim.x * gridDim.y * gridDim.z);
    int lid = blockIdx.x + (int)gridDim.x*(blockIdx.y + (int)gridDim.y*blockIdx.z);
    int swz = (lid & 7)*(nwg >> 3) + (lid >> 3);
    int ms = swz % MSn;
    int rem_ = swz / MSn;
    int nb = rem_ % 48;
    int bhl = rem_ / 48;
    int bh = g0 + bhl;
    int n0 = nb * 64;
    int msBase = ms * (Nn/MSn);
    const u16* qp = qh + ((size_t)bh*Nn + n0)*HDn;
    const u16* kp = kh + (size_t)bh*Nn*HDn;
    u16* pw = P2 + (size_t)bhl*Nn*Nn;     // LOCAL bh slice
    int wm = w & 1, wn = w >> 1;

    // stage Q tile into Ks region, preload fragments, then overwrite with K
    #pragma unroll
    for (int i = 0; i < 8; ++i) {
        int e = tid + i*256;
        int row = e >> 5, seg = e & 31;
        *(u16x8*)&Ks[row*264 + seg*8] = *(const u16x8*)(qp + (size_t)row*HDn + seg*8);
    }
    __syncthreads();
    bf16x8 qf[2][8];
    #pragma unroll
    for (int nt = 0; nt < 2; ++nt)
        #pragma unroll
        for (int ks = 0; ks < 8; ++ks)
            qf[nt][ks] = ld_frag16(&Ks[((2*wn+nt)*16 + l15)*264 + ks*32 + quad*8]);

    const int kr = tid >> 5, ksg = tid & 31;
    u16x8 kreg[8];
    #pragma unroll
    for (int i = 0; i < 8; ++i)
        kreg[i] = *(const u16x8*)(kp + (size_t)(msBase + kr + 8*i)*HDn + ksg*8);

    // exclusive C slot for this block's wn wave-pair
    float* cpart = C_part + ((size_t)(nb*2 + wn)*BHn + bh)*Nn;
    float rAcc[2] = {0.f, 0.f};
    const int NCH = Nn/(MSn*64);          // 6 chunks per slice
    for (int mc = 0; mc < NCH; ++mc) {
        int m0 = msBase + mc*64;
        int m0n = msBase + ((mc + 1 < NCH) ? (mc + 1)*64 : 0);
        __syncthreads();       // qf reads (mc=0) / previous MFMA reads done
        #pragma unroll
        for (int i = 0; i < 8; ++i)
            *(u16x8*)&Ks[(kr + 8*i)*264 + ksg*8] = kreg[i];
        __syncthreads();
        #pragma unroll
        for (int i = 0; i < 8; ++i)
            kreg[i] = *(const u16x8*)(kp + (size_t)(m0n + kr + 8*i)*HDn + ksg*8);
        f32x4 sacc[2][2];
        #pragma unroll
        for (int i = 0; i < 2; ++i)
            #pragma unroll
            for (int j = 0; j < 2; ++j) sacc[i][j] = (f32x4){0.f,0.f,0.f,0.f};
        #pragma unroll
        for (int ks = 0; ks < 8; ++ks) {
            bf16x8 a0 = ld_frag16(&Ks[((2*wm+0)*16 + l15)*264 + ks*32 + quad*8]);
            bf16x8 a1 = ld_frag16(&Ks[((2*wm+1)*16 + l15)*264 + ks*32 + quad*8]);
            sacc[0][0] = MFMA(a0, qf[0][ks], sacc[0][0]);
            sacc[0][1] = MFMA(a0, qf[1][ks], sacc[0][1]);
            sacc[1][0] = MFMA(a1, qf[0][ks], sacc[1][0]);
            sacc[1][1] = MFMA(a1, qf[1][ks], sacc[1][1]);
        }
        float ex[2][2][4];
        #pragma unroll
        for (int mt = 0; mt < 2; ++mt)
            #pragma unroll
            for (int nt = 0; nt < 2; ++nt)
                #pragma unroll
                for (int r = 0; r < 4; ++r)
                    ex[mt][nt][r] = __expf(0.0625f * sacc[mt][nt][r]);
        // P2 = ex^2 (== exp(0.125*S)), bf16, [n][m] with m-contig u16x4
        #pragma unroll
        for (int mt = 0; mt < 2; ++mt)
            #pragma unroll
            for (int nt = 0; nt < 2; ++nt) {
                u16x4 pk;
                #pragma unroll
                for (int r = 0; r < 4; ++r) {
                    float e2 = ex[mt][nt][r];
                    pk[r] = f2bf(e2 * e2);
                }
                *(u16x4*)(pw + (size_t)(n0 + (2*wn+nt)*16 + l15)*Nn
                             + m0 + (2*wm+mt)*16 + quad*4) = pk;
            }
        #pragma unroll
        for (int nt = 0; nt < 2; ++nt)
            #pragma unroll
            for (int mt = 0; mt < 2; ++mt)
                #pragma unroll
                for (int r = 0; r < 4; ++r) rAcc[nt] += ex[mt][nt][r];
        // C partial via merge-network (8 bpermute vs 32):
        {
            float v0 = ex[0][0][0] + ex[0][1][0];
            float v1 = ex[0][0][1] + ex[0][1][1];
            float v2 = ex[0][0][2] + ex[0][1][2];
            float v3 = ex[0][0][3] + ex[0][1][3];
            float v4 = ex[1][0][0] + ex[1][1][0];
            float v5 = ex[1][0][1] + ex[1][1][1];
            float v6 = ex[1][0][2] + ex[1][1][2];
            float v7 = ex[1][0][3] + ex[1][1][3];
            int b0 = l15 & 1, b1 = l15 & 2, b2 = l15 & 4;
            float u01 = (b0 ? v1 : v0) + __shfl_xor(b0 ? v0 : v1, 1, 16);
            float u23 = (b0 ? v3 : v2) + __shfl_xor(b0 ? v2 : v3, 1, 16);
            float u45 = (b0 ? v5 : v4) + __shfl_xor(b0 ? v4 : v5, 1, 16);
            float u67 = (b0 ? v7 : v6) + __shfl_xor(b0 ? v6 : v7, 1, 16);
            float t03 = (b1 ? u23 : u01) + __shfl_xor(b1 ? u01 : u23, 2, 16);
            float t47 = (b1 ? u67 : u45) + __shfl_xor(b1 ? u45 : u67, 2, 16);
            float s07 = (b2 ? t47 : t03) + __shfl_xor(b2 ? t03 : t47, 4, 16);
            s07 += __shfl_xor(s07, 8, 16);
            if (l15 < 8)
                cpart[m0 + (2*wm + (l15 >> 2))*16 + quad*4 + (l15 & 3)] = s07;
        }
    }
    // R: shfl reduces quad; cross-wm combine via LDS; wm==0 writes the slot.
    #pragma unroll
    for (int nt = 0; nt < 2; ++nt) {
        float rp = rAcc[nt];
        rp += __shfl_xor(rp, 16, 64);
        rp += __shfl_xor(rp, 32, 64);
        if (quad == 0) rbuf[wm][nt][wn*32 + l15] = rp;
    }
    __syncthreads();
    #pragma unroll
    for (int nt = 0; nt < 2; ++nt) {
        if (quad == 0 && wm == 0) {
            float tot = rbuf[0][nt][wn*32 + l15] + rbuf[1][nt][wn*32 + l15];
            R_part[(size_t)ms*BHn*Nn + (size_t)bh*Nn + n0 + (2*wn+nt)*16 + l15] = tot;
        }
    }
}

// ---------------------------------------------------------------------------
// K2b: per-group inverse sums. Pointers pre-offset by g0*Nn; i spans gbh*Nn.
// ---------------------------------------------------------------------------
__global__ void inv_kernel(const float* __restrict__ Rg,
                           const float* __restrict__ Cg,
                           float* __restrict__ iRg, float* __restrict__ iCg) {
    int i = blockIdx.x * blockDim.x + threadIdx.x;
    float r = 0.f;
    #pragma unroll
    for (int s = 0; s < MSn; ++s)
        r += Rg[(size_t)s*BHn*Nn + i];
    float c = 0.f;
    for (int s = 0; s < 96; ++s)
        c += Cg[(size_t)s*BHn*Nn + i];
    iRg[i] = 1.0f / r;
    iCg[i] = 1.0f / c;
}

// ---------------------------------------------------------------------------
// K2c: vTs[bhl][e][m] = vT[bh][e][m] * iC[bh][m] for the group's bh slice.
// ---------------------------------------------------------------------------
__global__ void scale_v(const u16* __restrict__ vTg, const float* __restrict__ iCg,
                        u16* __restrict__ vTs) {
    int idx = blockIdx.x * blockDim.x + threadIdx.x;   // gbh*EP*Nn/8 threads
    int bhl = idx / (EP*Nn/8);
    int rem = idx - bhl*(EP*Nn/8);
    size_t off = (size_t)bhl*EP*Nn + (size_t)rem*8;
    int m = (rem % (Nn/8)) * 8;
    u16x8 v = *(const u16x8*)(vTg + off);
    float4 c0 = *(const float4*)(iCg + (size_t)bhl*Nn + m);
    float4 c1 = *(const float4*)(iCg + (size_t)bhl*Nn + m + 4);
    u16x8 o;
    o[0]=f2bf(bf2f(v[0])*c0.x); o[1]=f2bf(bf2f(v[1])*c0.y);
    o[2]=f2bf(bf2f(v[2])*c0.z); o[3]=f2bf(bf2f(v[3])*c0.w);
    o[4]=f2bf(bf2f(v[4])*c1.x); o[5]=f2bf(bf2f(v[5])*c1.y);
    o[6]=f2bf(bf2f(v[6])*c1.z); o[7]=f2bf(bf2f(v[7])*c1.w);
    *(u16x8*)(vTs + off) = o;
}

// ---------------------------------------------------------------------------
// K3 (R21): pure PV GEMM, z-split with LEAN V staging + XCD swizzle.
//   f1aT[e][n] = iR[n] * sum_m P2[n][m] * vTs[e][m]
// ---------------------------------------------------------------------------
__global__ __launch_bounds__(256, 4) void pv_mfma(const u16* __restrict__ P2,
                                                  const u16* __restrict__ vTs,
                                                  const float* __restrict__ iRg,
                                                  u16* __restrict__ f1aTg) {
    __shared__ u16 Ps2[64*72];    //  9216 B  (P chunk, rows n, pad->72)
    __shared__ u16 Vt[144*72];    // 20736 B  (this z-half's V rows, pad->72)
    int tid = threadIdx.x;
    int w = tid >> 6, lane = tid & 63, quad = lane >> 4, l15 = lane & 15;
    // XCD-chunked remap (nwg = 48*gbh*2, divisible by 8)
    int nwg = (int)(gridDim.x * gridDim.y * gridDim.z);
    int lid = blockIdx.x + (int)gridDim.x*(blockIdx.y + (int)gridDim.y*blockIdx.z);
    int swz = (lid & 7)*(nwg >> 3) + (lid >> 3);
    int n0b = swz % 48;
    int rem_ = swz / 48;
    int bhl = rem_ % (int)gridDim.y;
    int z = rem_ / (int)gridDim.y;     // 0: e-tiles 0..7; 1: e-tiles 8..16
    int n0 = n0b * 64;
    const u16* pp = P2  + ((size_t)bhl*Nn + n0)*Nn;
    const u16* vp = vTs + (size_t)bhl*EP*Nn + (size_t)(z*128)*Nn;  // z-half base
    const int sr = tid >> 3, sg = tid & 7;     // staging: rows sr+32i, seg sg
    u16x8 preg[2], vreg[5];
    // prefetch chunk 0 (V: 128 rows for z=0, 144 for z=1)
    #pragma unroll
    for (int i = 0; i < 2; ++i)
        preg[i] = *(const u16x8*)(pp + (size_t)(sr + 32*i)*Nn + sg*8);
    #pragma unroll
    for (int i = 0; i < 5; ++i)
        if (i < 4 || (z == 1 && tid < 128))
            vreg[i] = *(const u16x8*)(vp + (size_t)(sr + 32*i)*Nn + sg*8);

    f32x4 acc[4][3];
    #pragma unroll
    for (int a = 0; a < 4; ++a)
        #pragma unroll
        for (int b = 0; b < 3; ++b) acc[a][b] = (f32x4){0.f,0.f,0.f,0.f};

    for (int mc = 0; mc < Nn/64; ++mc) {
        int m0n = (mc + 1 < Nn/64) ? (mc + 1)*64 : 0;   // clamped next chunk
        __syncthreads();   // previous chunk's LDS readers done
        #pragma unroll
        for (int i = 0; i < 2; ++i)
            *(u16x8*)&Ps2[(sr + 32*i)*72 + sg*8] = preg[i];
        #pragma unroll
        for (int i = 0; i < 5; ++i)
            if (i < 4 || (z == 1 && tid < 128))
                *(u16x8*)&Vt[(sr + 32*i)*72 + sg*8] = vreg[i];
        __syncthreads();
        // issue prefetch for next chunk (overlaps MFMA below)
        #pragma unroll
        for (int i = 0; i < 2; ++i)
            preg[i] = *(const u16x8*)(pp + (size_t)(sr + 32*i)*Nn + m0n + sg*8);
        #pragma unroll
        for (int i = 0; i < 5; ++i)
            if (i < 4 || (z == 1 && tid < 128))
                vreg[i] = *(const u16x8*)(vp + (size_t)(sr + 32*i)*Nn + m0n + sg*8);
        // acc += P2 · vTs^T   (A = Ps2[n][m], B = Vt[e_local][m])
        #pragma unroll
        for (int ks = 0; ks < 2; ++ks) {
            bf16x8 pa[4];
            #pragma unroll
            for (int nt = 0; nt < 4; ++nt)
                pa[nt] = ld_frag16(&Ps2[(nt*16 + l15)*72 + ks*32 + quad*8]);
            #pragma unroll
            for (int et = 0; et < 3; ++et) {
                const int lt = (et < 2) ? (w*2 + et) : 8;   // local tile in Vt
                const bool act = (et < 2 || (z == 1 && w == 3));
                if (act) {   // wave-uniform; static indices
                    bf16x8 vb = ld_frag16(&Vt[(lt*16 + l15)*72 + ks*32 + quad*8]);
                    #pragma unroll
                    for (int nt = 0; nt < 4; ++nt)
                        acc[nt][et] = MFMA(pa[nt], vb, acc[nt][et]);
                }
            }
        }
    }
    // epilogue: scale by invR[n], pack bf16, store transposed f1aT[e][n]
    #pragma unroll
    for (int nt = 0; nt < 4; ++nt) {
        float4 ir4 = *(const float4*)(iRg + (size_t)bhl*Nn + n0 + nt*16 + quad*4);
        #pragma unroll
        for (int et = 0; et < 3; ++et) {
            const int tile = (et < 2) ? (z*8 + w*2 + et) : 16;
            const bool act = (et < 2 || (z == 1 && w == 3));
            if (act) {
                int e = tile*16 + l15;
                u16x4 ov;
                #pragma unroll
                for (int r = 0; r < 4; ++r)
                    ov[r] = f2bf(acc[nt][et][r] * ((const float*)&ir4)[r]);
                *(u16x4*)(f1aTg + ((size_t)bhl*EP + e)*Nn + n0 + nt*16 + quad*4) = ov;
            }
        }
    }
}

// ---------------------------------------------------------------------------
// K4 (R21): fund_part[ks][bh][d][e] = sum_{n in ks-slice} vT[d][n]*f1aT[e][n].
// Register-prefetch double-stage + K-split KSn=4 (1200 blocks) + XCD swizzle.
// ---------------------------------------------------------------------------
__global__ __launch_bounds__(256) void fund_mfma(const u16* __restrict__ vT,
                                                 const u16* __restrict__ f1aT,
                                                 float* __restrict__ fund_part) {
    __shared__ u16 At[64*136];
    __shared__ u16 Bt[64*136];
    int tid = threadIdx.x;
    int w = tid >> 6, lane = tid & 63, quad = lane >> 4, l15 = lane & 15;
    // XCD-chunked remap (nwg = 5*5*48 = 1200, divisible by 8)
    int lid = blockIdx.x + 5*(blockIdx.y + 5*blockIdx.z);
    int swz = (lid & 7)*150 + (lid >> 3);
    int ex_ = swz % 5;
    int rem_ = swz / 5;
    int dx_ = rem_ % 5;
    int bz = rem_ / 5;
    int bh = bz >> 2;            // KSn = 4
    int ks = bz & 3;
    int d0 = dx_ * 64, e0 = ex_ * 64;
    const u16* ap = vT   + (size_t)bh*EP*Nn;
    const u16* bp = f1aT + (size_t)bh*EP*Nn;
    int wd = w & 1, we = w >> 1;
    const u16x8 zero8 = {0,0,0,0,0,0,0,0};
    const int nc0 = ks * (Nn/KSn);          // 768-wide K slice
    const int NCH = (Nn/KSn)/128;           // 6 chunks

    const int srow = tid >> 4, seg = tid & 15;   // staging rows srow+16i
    u16x8 areg[4], breg[4];
    #pragma unroll
    for (int i = 0; i < 4; ++i) {
        int row = srow + 16*i;
        int da = d0 + row, eb = e0 + row;
        areg[i] = (da < EP) ? *(const u16x8*)(ap + (size_t)da*Nn + nc0 + seg*8) : zero8;
        breg[i] = (eb < EP) ? *(const u16x8*)(bp + (size_t)eb*Nn + nc0 + seg*8) : zero8;
    }

    f32x4 acc[2][2];
    #pragma unroll
    for (int i = 0; i < 2; ++i)
        #pragma unroll
        for (int j = 0; j < 2; ++j) acc[i][j] = (f32x4){0.f,0.f,0.f,0.f};

    for (int mc = 0; mc < NCH; ++mc) {
        int ncn = nc0 + ((mc + 1 < NCH) ? (mc + 1)*128 : 0);
        __syncthreads();
        #pragma unroll
        for (int i = 0; i < 4; ++i) {
            int row = srow + 16*i;
            *(u16x8*)&At[row*136 + seg*8] = areg[i];
            *(u16x8*)&Bt[row*136 + seg*8] = breg[i];
        }
        __syncthreads();
        #pragma unroll
        for (int i = 0; i < 4; ++i) {
            int row = srow + 16*i;
            int da = d0 + row, eb = e0 + row;
            areg[i] = (da < EP) ? *(const u16x8*)(ap + (size_t)da*Nn + ncn + seg*8) : zero8;
            breg[i] = (eb < EP) ? *(const u16x8*)(bp + (size_t)eb*Nn + ncn + seg*8) : zero8;
        }
        #pragma unroll
        for (int kk = 0; kk < 4; ++kk) {
            bf16x8 a0 = ld_frag16(&At[((2*wd+0)*16 + l15)*136 + kk*32 + quad*8]);
            bf16x8 a1 = ld_frag16(&At[((2*wd+1)*16 + l15)*136 + kk*32 + quad*8]);
            bf16x8 b0 = ld_frag16(&Bt[((2*we+0)*16 + l15)*136 + kk*32 + quad*8]);
            bf16x8 b1 = ld_frag16(&Bt[((2*we+1)*16 + l15)*136 + kk*32 + quad*8]);
            acc[0][0] = MFMA(a0, b0, acc[0][0]);
            acc[0][1] = MFMA(a0, b1, acc[0][1]);
            acc[1][0] = MFMA(a1, b0, acc[1][0]);
            acc[1][1] = MFMA(a1, b1, acc[1][1]);
        }
    }
    float* fp = fund_part + (size_t)(ks*BHn + bh)*Dn*FP;
    #pragma unroll
    for (int dt = 0; dt < 2; ++dt)
        #pragma unroll
        for (int et = 0; et < 2; ++et)
            #pragma unroll
            for (int r = 0; r < 4; ++r) {
                int d = d0 + (2*wd+dt)*16 + quad*4 + r;
                int e = e0 + (2*we+et)*16 + l15;
                if (d < Dn && e < Dn)
                    fp[(size_t)d*FP + e] = acc[dt][et][r];
            }
}

// ---------------------------------------------------------------------------
// K5 (R19): out[b,d2,o] = sum_j (sum_ks fund_part[ks])[...] * WpfT[j][o]+bpf
// ---------------------------------------------------------------------------
__device__ __forceinline__ float4 ld4sum(const float* p, size_t SL) {
    float4 a = *(const float4*)p;
    float4 b = *(const float4*)(p + SL);
    float4 c = *(const float4*)(p + 2*SL);
    float4 d = *(const float4*)(p + 3*SL);
    return (float4){a.x+b.x+c.x+d.x, a.y+b.y+c.y+d.y,
                    a.z+b.z+c.z+d.z, a.w+b.w+c.w+d.w};
}

__global__ __launch_bounds__(256) void out_gemm(const float* __restrict__ fund_part,
                                                const float* __restrict__ WpfT,
                                                const float* __restrict__ bpf,
                                                float* __restrict__ out) {
    __shared__ float As[2][16][68];
    __shared__ float Bs[2][16][68];
    const size_t SL = (size_t)BHn*Dn*FP;   // ks-slice stride (floats)
    int tid = threadIdx.x;
    int b_ = blockIdx.z;
    int d2b = blockIdx.y * 64, ob = blockIdx.x * 64;
    int ty = tid >> 4, tx = tid & 15;      // 4x4 outputs at (d2b+ty*4, ob+tx*4)
    int srow = tid >> 4, sc4 = (tid & 15) * 4;   // staging: j row, 4-col seg
    const int NIT = (786 + 15) / 16;       // 50

    float4 aReg, bReg;
    {   // chunk 0
        int j = srow;
        int h = j / Dn, d1 = j - h*Dn;
        const float* srcA = fund_part + ((size_t)(b_*Hn + h)*Dn + d1)*FP + d2b + sc4;
        if (d2b + sc4 + 3 < Dn) aReg = ld4sum(srcA, SL);
        else {
            float t[4] = {0.f,0.f,0.f,0.f};
            for (int u2 = 0; u2 < 4; ++u2)
                if (d2b + sc4 + u2 < Dn)
                    t[u2] = srcA[u2] + srcA[u2+SL] + srcA[u2+2*SL] + srcA[u2+3*SL];
            aReg = (float4){t[0],t[1],t[2],t[3]};
        }
        bReg = *(const float4*)(WpfT + (size_t)j*768 + ob + sc4);
    }
    *(float4*)&As[0][srow][sc4] = aReg;
    *(float4*)&Bs[0][srow][sc4] = bReg;
    __syncthreads();

    float acc[4][4] = {};
    for (int c = 0; c < NIT; ++c) {
        int buf = c & 1;
        if (c + 1 < NIT) {   // prefetch next chunk (global -> regs)
            int j = (c + 1)*16 + srow;
            aReg = (float4){0.f,0.f,0.f,0.f};
            bReg = (float4){0.f,0.f,0.f,0.f};
            if (j < 786) {
                int h = j / Dn, d1 = j - h*Dn;
                const float* srcA = fund_part + ((size_t)(b_*Hn + h)*Dn + d1)*FP + d2b + sc4;
                if (d2b + sc4 + 3 < Dn) aReg = ld4sum(srcA, SL);
                else {
                    float t[4] = {0.f,0.f,0.f,0.f};
                    for (int u2 = 0; u2 < 4; ++u2)
                        if (d2b + sc4 + u2 < Dn)
                            t[u2] = srcA[u2] + srcA[u2+SL] + srcA[u2+2*SL] + srcA[u2+3*SL];
                    aReg = (float4){t[0],t[1],t[2],t[3]};
                }
                bReg = *(const float4*)(WpfT + (size_t)j*768 + ob + sc4);
            }
        }
        #pragma unroll
        for (int kk = 0; kk < 16; ++kk) {
            float4 a = *(const float4*)&As[buf][kk][ty*4];
            float4 b = *(const float4*)&Bs[buf][kk][tx*4];
            acc[0][0] += a.x*b.x; acc[0][1] += a.x*b.y; acc[0][2] += a.x*b.z; acc[0][3] += a.x*b.w;
            acc[1][0] += a.y*b.x; acc[1][1] += a.y*b.y; acc[1][2] += a.y*b.z; acc[1][3] += a.y*b.w;
            acc[2][0] += a.z*b.x; acc[2][1] += a.z*b.y; acc[2][2] += a.z*b.z; acc[2][3] += a.z*b.w;
            acc[3][0] += a.w*b.x; acc[3][1] += a.w*b.y; acc[3][2] += a.w*b.z; acc[3][3] += a.w*b.w;
        }
        if (c + 1 < NIT) {
            *(float4*)&As[buf^1][srow][sc4] = aReg;
            *(float4*)&Bs[buf^1][srow][sc4] = bReg;
            __syncthreads();
        }
    }
    #pragma unroll
    for (int i = 0; i < 4; ++i) {
        int d2 = d2b + ty*4 + i;
        if (d2 >= Dn) continue;
        #pragma unroll
        for (int j = 0; j < 4; ++j) {
            int o = ob + tx*4 + j;
            out[((size_t)b_*Dn + d2)*DIMn + o] = acc[i][j] + bpf[o];
        }
    }
}

// ---------------------------------------------------------------------------
// Workspace (ws_size-adaptive):
//   fixed region (~108 MB): qh kh vT f1aT Cp iR iC fund_part(KSn slices) WpfT
//   region2 = max(xb+Wb staging [22.4 MB], gbh*(P2+vTs) + Rp)
//   gbh = largest of {12,6,4,3,2,1} that fits ws_size.
// ---------------------------------------------------------------------------
extern "C" void kernel_launch(void* const* d_in, const int* in_sizes, int n_in,
                              void* d_out, int out_size, void* d_ws, size_t ws_size,
                              hipStream_t stream) {
    const float* x    = (const float*)d_in[0];   // [4,3072,768]
    const float* Wqkv = (const float*)d_in[1];   // [2304,768]
    const float* Wpf  = (const float*)d_in[2];   // [768,786]
    const float* bpf  = (const float*)d_in[3];   // [768]
    float* out = (float*)d_out;                  // [4,262,768]

    char* p = (char*)d_ws;
    u16* qh    = (u16*)p;                       p += (size_t)BHn*Nn*HDn*2;   // 18.87 MB
    u16* kh    = (u16*)p;                       p += (size_t)BHn*Nn*HDn*2;   // 18.87 MB
    u16* vT    = (u16*)p;                       p += (size_t)BHn*EP*Nn*2;    // 20.05 MB
    u16* f1aT  = (u16*)p;                       p += (size_t)BHn*EP*Nn*2;    // 20.05 MB
    float* Cp  = (float*)p;                     p += (size_t)96*BHn*Nn*4;    // 14.16 MB
    float* iR  = (float*)p;                     p += (size_t)BHn*Nn*4;
    float* iC  = (float*)p;                     p += (size_t)BHn*Nn*4;
    float* fund= (float*)p;                     p += (size_t)KSn*BHn*Dn*FP*4 + 256; // 13.3 MB
    float* WpfT= (float*)p;                     p += (size_t)786*768*4;      // 2.41 MB
    char* region2 = p;
    size_t fixedB = (size_t)(region2 - (char*)d_ws);
    size_t avail = (ws_size > fixedB) ? (ws_size - fixedB) : 0;

    const size_t perBh = ((size_t)Nn*Nn + (size_t)EP*Nn) * 2;   // 20,545,536
    const size_t rpB   = (size_t)MSn*BHn*Nn*4;                  //  1,179,648
    int gbh = 1;
    const int cand[5] = {12, 6, 4, 3, 2};
    for (int ci = 0; ci < 5; ++ci) {
        if ((size_t)cand[ci]*perBh + rpB <= avail) { gbh = cand[ci]; break; }
    }

    // qkv staging view of region2 (dead after qkv_mfma)
    u16* xb = (u16*)region2;
    u16* Wb = xb + (size_t)Bn*Nn*DIMn;
    // group-pipeline view of region2 (live from rc_mfma on)
    u16* P2  = (u16*)region2;
    u16* vTs = P2 + (size_t)gbh*Nn*Nn;
    float* Rp = (float*)(vTs + (size_t)gbh*EP*Nn);

    to_bf16  <<<dim3((Bn*Nn*DIMn/8 + 255)/256), 256, 0, stream>>>(x, xb, Bn*Nn*DIMn/8);
    to_bf16  <<<dim3((3*DIMn*DIMn/8 + 255)/256), 256, 0, stream>>>(Wqkv, Wb, 3*DIMn*DIMn/8);
    transpose_wpf<<<dim3(25, 24), 256, 0, stream>>>(Wpf, WpfT);
    qkv_mfma <<<dim3(18, 96), 256, 0, stream>>>(xb, Wb, qh, kh, vT);
    pos_fill <<<dim3(BHn*16*Nn/256), 256, 0, stream>>>(vT);

    for (int g0 = 0; g0 < BHn; g0 += gbh) {
        rc_mfma  <<<dim3(MSn, Nn/64, gbh), 256, 0, stream>>>(qh, kh, Rp, Cp, P2, g0);
        inv_kernel<<<dim3(gbh*Nn/256), 256, 0, stream>>>(
            Rp + (size_t)g0*Nn, Cp + (size_t)g0*Nn, iR + (size_t)g0*Nn, iC + (size_t)g0*Nn);
        scale_v  <<<dim3(gbh*EP*Nn/8/256), 256, 0, stream>>>(
            vT + (size_t)g0*EP*Nn, iC + (size_t)g0*Nn, vTs);
        pv_mfma  <<<dim3(Nn/64, gbh, 2), 256, 0, stream>>>(
            P2, vTs, iR + (size_t)g0*Nn, f1aT + (size_t)g0*EP*Nn);
    }

    fund_mfma<<<dim3(5, 5, BHn*KSn), 256, 0, stream>>>(vT, f1aT, fund);
    out_gemm <<<dim3(DIMn/64, 5, Bn), 256, 0, stream>>>(fund, WpfT, bpf, out);
}